// Round 9
// baseline (342.693 us; speedup 1.0000x reference)
//
#include <hip/hip_runtime.h>

#define N_NODES 50000
#define N_EDGES 640000
#define NSCANB  196   // ceil(50000/256)

// workspace layout (4B units)
#define OFF_HTMPB    0          // ushort[6400000] bf16 h=xW
#define OFF_OBF      3200000    // ushort[6400000] bf16 copy of out
#define OFF_DEG      6400000    // int[50000]
#define OFF_ROWSTART 6450000    // int[50001]
#define OFF_CURSOR   6500016    // int[50000]
#define OFF_DINV     6550016    // float[50000]
#define OFF_E        6600016    // float[50000]
#define OFF_SCAL     6650016    // [0]=EminBits [1]=S0 [2]=S1
#define OFF_BAR      6650020    // int[2] grid-barrier counters
#define OFF_BLKSUM   6650024    // int[256]
#define OFF_ESRC     6650280    // int[640000]

typedef __attribute__((ext_vector_type(4))) short bf16x4;
typedef __attribute__((ext_vector_type(8))) short bf16x8;
typedef __attribute__((ext_vector_type(4))) float f32x4;

__device__ __forceinline__ unsigned short f2bf(float f) {  // RNE
    unsigned u = __float_as_uint(f);
    unsigned r = u + 0x7fffu + ((u >> 16) & 1u);
    return (unsigned short)(r >> 16);
}
__device__ __forceinline__ float bflo(unsigned u) { return __uint_as_float(u << 16); }
__device__ __forceinline__ float bfhi(unsigned u) { return __uint_as_float(u & 0xffff0000u); }

__global__ __launch_bounds__(256) void k_init(float* ws) {
    int i = blockIdx.x * 256 + threadIdx.x;
    if (i < N_NODES) ((int*)(ws + OFF_DEG))[i] = 0;
    if (i == 0) {
        ((int*)(ws + OFF_SCAL))[0] = 0x7F7FFFFF;  // FLT_MAX bits
        ws[OFF_SCAL + 1] = 0.f;
        ws[OFF_SCAL + 2] = 0.f;
        ((int*)(ws + OFF_BAR))[0] = 0;
        ((int*)(ws + OFF_BAR))[1] = 0;
    }
}

// Fused: degree atomics (grid-stride prologue) + bf16 MFMA GEMM (64-row tile/block).
__global__ __launch_bounds__(256) void k_deg_gemm(const float* __restrict__ x,
                                                  const int* __restrict__ dst,
                                                  const float* __restrict__ W,
                                                  int* __restrict__ deg,
                                                  unsigned short* __restrict__ htmpb) {
    int gtid = blockIdx.x * 256 + threadIdx.x;
    for (int e = gtid; e < N_EDGES; e += 782 * 256) atomicAdd(&deg[dst[e]], 1);

    __shared__ unsigned short wt[128 * 132];   // bf16 W^T
    int tid = threadIdx.x;
    for (int i = tid; i < 4096; i += 256) {
        int k = i >> 5, n4 = (i & 31) * 4;
        float4 v = *(const float4*)(W + k * 128 + n4);
        wt[(n4 + 0) * 132 + k] = f2bf(v.x);
        wt[(n4 + 1) * 132 + k] = f2bf(v.y);
        wt[(n4 + 2) * 132 + k] = f2bf(v.z);
        wt[(n4 + 3) * 132 + k] = f2bf(v.w);
    }
    __syncthreads();

    int wave = tid >> 6, lane = tid & 63, quad = lane >> 4, m16 = lane & 15;
    int r0 = blockIdx.x * 64;
    int arow = r0 + wave * 16 + m16;
    int rowc = arow < N_NODES ? arow : N_NODES - 1;
    f32x4 acc[8];
    #pragma unroll
    for (int c = 0; c < 8; c++) acc[c] = (f32x4){0.f, 0.f, 0.f, 0.f};
    #pragma unroll
    for (int kt = 0; kt < 4; kt++) {
        int koff = kt * 32 + quad * 8;
        float4 xa = *(const float4*)(x + rowc * 128 + koff);
        float4 xb = *(const float4*)(x + rowc * 128 + koff + 4);
        bf16x8 af;
        af[0] = (short)f2bf(xa.x); af[1] = (short)f2bf(xa.y);
        af[2] = (short)f2bf(xa.z); af[3] = (short)f2bf(xa.w);
        af[4] = (short)f2bf(xb.x); af[5] = (short)f2bf(xb.y);
        af[6] = (short)f2bf(xb.z); af[7] = (short)f2bf(xb.w);
        #pragma unroll
        for (int c = 0; c < 8; c++) {
            bf16x4 bl = *(const bf16x4*)(wt + (c * 16 + m16) * 132 + koff);
            bf16x4 bh = *(const bf16x4*)(wt + (c * 16 + m16) * 132 + koff + 4);
            bf16x8 bfrag = __builtin_shufflevector(bl, bh, 0, 1, 2, 3, 4, 5, 6, 7);
            acc[c] = __builtin_amdgcn_mfma_f32_16x16x32_bf16(af, bfrag, acc[c], 0, 0, 0);
        }
    }
    #pragma unroll
    for (int reg = 0; reg < 4; reg++) {
        int grow = r0 + wave * 16 + quad * 4 + reg;
        if (grow < N_NODES) {
            #pragma unroll
            for (int c = 0; c < 8; c++)
                htmpb[grow * 128 + c * 16 + m16] = f2bf(acc[c][reg]);
        }
    }
}

__global__ __launch_bounds__(256) void k_scan1(const int* __restrict__ deg,
                                               int* __restrict__ rowstart,
                                               int* __restrict__ blksum,
                                               float* __restrict__ dinv) {
    __shared__ int sh[256];
    int i = blockIdx.x * 256 + threadIdx.x;
    int v = (i < N_NODES) ? deg[i] : 0;
    if (i < N_NODES) dinv[i] = rsqrtf((float)(v + 1));  // +1 self-loop
    sh[threadIdx.x] = v;
    __syncthreads();
    #pragma unroll
    for (int off = 1; off < 256; off <<= 1) {
        int t = (threadIdx.x >= off) ? sh[threadIdx.x - off] : 0;
        __syncthreads();
        sh[threadIdx.x] += t;
        __syncthreads();
    }
    if (i < N_NODES) rowstart[i] = sh[threadIdx.x] - v;
    if (threadIdx.x == 255) blksum[blockIdx.x] = sh[255];
}

__global__ __launch_bounds__(256) void k_scan23(int* __restrict__ rowstart,
                                                const int* __restrict__ blksum,
                                                int* __restrict__ cursor) {
    __shared__ int ired[4];
    int vb = blockIdx.x, tid = threadIdx.x;
    int lane = tid & 63, wid = tid >> 6;
    int p = (tid < vb) ? blksum[tid] : 0;   // vb <= 195 < 256
    #pragma unroll
    for (int off = 32; off; off >>= 1) p += __shfl_xor(p, off);
    if (lane == 0) ired[wid] = p;
    __syncthreads();
    int offp = ired[0] + ired[1] + ired[2] + ired[3];
    int i = vb * 256 + tid;
    if (i < N_NODES) { rowstart[i] += offp; cursor[i] = 0; }
    if (vb == 0 && tid == 0) rowstart[N_NODES] = N_EDGES;
}

__global__ __launch_bounds__(256) void k_bucket(const int* __restrict__ src,
                                                const int* __restrict__ dst,
                                                const int* __restrict__ rowstart,
                                                int* __restrict__ cursor,
                                                int* __restrict__ esrc) {
    int e = blockIdx.x * 256 + threadIdx.x;
    int d = dst[e];
    int pos = atomicAdd(&cursor[d], 1);
    esrc[rowstart[d] + pos] = src[e];
}

// per node (32 lanes, 4 bf16/lane via uint2), 4 independent load chains.
__global__ __launch_bounds__(256) void k_gather(const unsigned short* __restrict__ htmpb,
                                                const float* __restrict__ dinv,
                                                const float* __restrict__ b,
                                                const int* __restrict__ rowstart,
                                                const int* __restrict__ esrc,
                                                float* __restrict__ out,
                                                unsigned short* __restrict__ obf) {
    int node = blockIdx.x * 8 + (threadIdx.x >> 5);
    int lane = threadIdx.x & 31;
    float di = dinv[node];
    float4 bv = *(const float4*)(b + lane * 4);
    uint2 hv = *(const uint2*)(htmpb + node * 128 + lane * 4);
    float sl = di * di;
    float ax = bv.x + bflo(hv.x) * sl, ay = bv.y + bfhi(hv.x) * sl;
    float az = bv.z + bflo(hv.y) * sl, aw = bv.w + bfhi(hv.y) * sl;
    float cx = 0.f, cy = 0.f, cz = 0.f, cw = 0.f;
    int e0 = rowstart[node], e1 = rowstart[node + 1];
    int k = e0;
    for (; k + 3 < e1; k += 4) {
        int s0 = esrc[k], s1 = esrc[k + 1], s2 = esrc[k + 2], s3 = esrc[k + 3];
        float n0 = di * dinv[s0], n1 = di * dinv[s1];
        float n2 = di * dinv[s2], n3 = di * dinv[s3];
        uint2 u0 = *(const uint2*)(htmpb + s0 * 128 + lane * 4);
        uint2 u1 = *(const uint2*)(htmpb + s1 * 128 + lane * 4);
        uint2 u2 = *(const uint2*)(htmpb + s2 * 128 + lane * 4);
        uint2 u3 = *(const uint2*)(htmpb + s3 * 128 + lane * 4);
        ax += bflo(u0.x) * n0; ay += bfhi(u0.x) * n0;
        az += bflo(u0.y) * n0; aw += bfhi(u0.y) * n0;
        cx += bflo(u1.x) * n1; cy += bfhi(u1.x) * n1;
        cz += bflo(u1.y) * n1; cw += bfhi(u1.y) * n1;
        ax += bflo(u2.x) * n2; ay += bfhi(u2.x) * n2;
        az += bflo(u2.y) * n2; aw += bfhi(u2.y) * n2;
        cx += bflo(u3.x) * n3; cy += bfhi(u3.x) * n3;
        cz += bflo(u3.y) * n3; cw += bfhi(u3.y) * n3;
    }
    for (; k < e1; k++) {
        int s0 = esrc[k];
        float n0 = di * dinv[s0];
        uint2 u0 = *(const uint2*)(htmpb + s0 * 128 + lane * 4);
        ax += bflo(u0.x) * n0; ay += bfhi(u0.x) * n0;
        az += bflo(u0.y) * n0; aw += bfhi(u0.y) * n0;
    }
    ax += cx; ay += cy; az += cz; aw += cw;
    *(float4*)(out + node * 128 + lane * 4) = make_float4(ax, ay, az, aw);
    uint2 pk;
    pk.x = (unsigned)f2bf(ax) | ((unsigned)f2bf(ay) << 16);
    pk.y = (unsigned)f2bf(az) | ((unsigned)f2bf(aw) << 16);
    *(uint2*)(obf + node * 128 + lane * 4) = pk;
}

// per node: E[d] = sum ||out_s - out_d||^2 (bf16 gather, 4 chains, NO block barrier)
__global__ __launch_bounds__(256) void k_energy(const unsigned short* __restrict__ obf,
                                                const int* __restrict__ rowstart,
                                                const int* __restrict__ esrc,
                                                float* __restrict__ E) {
    int node = blockIdx.x * 8 + (threadIdx.x >> 5);
    int lane = threadIdx.x & 31;
    uint2 ud = *(const uint2*)(obf + node * 128 + lane * 4);
    float o0 = bflo(ud.x), o1 = bfhi(ud.x), o2 = bflo(ud.y), o3 = bfhi(ud.y);
    float acc = 0.f, acc2 = 0.f;
    int e0 = rowstart[node], e1 = rowstart[node + 1];
    int k = e0;
    for (; k + 3 < e1; k += 4) {
        int s0 = esrc[k], s1 = esrc[k + 1], s2 = esrc[k + 2], s3 = esrc[k + 3];
        uint2 a = *(const uint2*)(obf + s0 * 128 + lane * 4);
        uint2 c = *(const uint2*)(obf + s1 * 128 + lane * 4);
        uint2 g = *(const uint2*)(obf + s2 * 128 + lane * 4);
        uint2 h = *(const uint2*)(obf + s3 * 128 + lane * 4);
        float d0 = bflo(a.x) - o0, d1 = bfhi(a.x) - o1, d2 = bflo(a.y) - o2, d3 = bfhi(a.y) - o3;
        float e4 = bflo(c.x) - o0, e5 = bfhi(c.x) - o1, e6 = bflo(c.y) - o2, e7 = bfhi(c.y) - o3;
        float f0 = bflo(g.x) - o0, f1 = bfhi(g.x) - o1, f2 = bflo(g.y) - o2, f3 = bfhi(g.y) - o3;
        float h4 = bflo(h.x) - o0, h5 = bfhi(h.x) - o1, h6 = bflo(h.y) - o2, h7 = bfhi(h.y) - o3;
        acc  += d0 * d0 + d1 * d1 + d2 * d2 + d3 * d3;
        acc2 += e4 * e4 + e5 * e5 + e6 * e6 + e7 * e7;
        acc  += f0 * f0 + f1 * f1 + f2 * f2 + f3 * f3;
        acc2 += h4 * h4 + h5 * h5 + h6 * h6 + h7 * h7;
    }
    for (; k < e1; k++) {
        int s0 = esrc[k];
        uint2 a = *(const uint2*)(obf + s0 * 128 + lane * 4);
        float d0 = bflo(a.x) - o0, d1 = bfhi(a.x) - o1, d2 = bflo(a.y) - o2, d3 = bfhi(a.y) - o3;
        acc += d0 * d0 + d1 * d1 + d2 * d2 + d3 * d3;
    }
    acc += acc2;
    #pragma unroll
    for (int off = 16; off; off >>= 1) acc += __shfl_xor(acc, off);
    if (lane == 0) E[node] = acc;
}

// Tail: Emin -> (S0,S1) -> gradient, with 2 lightweight grid barriers.
// grid = 256 blocks (1/CU guaranteed co-resident).
__global__ __launch_bounds__(256) void k_tail(const int* __restrict__ rowstart,
                                              const int* __restrict__ esrc,
                                              const float* __restrict__ E,
                                              const float* __restrict__ temp,
                                              float* scal, int* bar,
                                              const float* __restrict__ weight,
                                              float* __restrict__ out) {
    __shared__ float fred[8];
    int tid = threadIdx.x;
    int gtid = blockIdx.x * 256 + tid;
    int gsz = gridDim.x * 256;
    int lane = tid & 63, wid = tid >> 6;

    // ---- A: Emin ----
    float v = 3.402823466e38f;
    for (int i = gtid; i < N_NODES; i += gsz) v = fminf(v, E[i]);
    #pragma unroll
    for (int off = 32; off; off >>= 1) v = fminf(v, __shfl_xor(v, off));
    if (lane == 0) fred[wid] = v;
    __syncthreads();
    if (tid == 0) {
        float m = fminf(fminf(fred[0], fred[1]), fminf(fred[2], fred[3]));
        atomicMin((int*)scal, __float_as_int(m));  // valid: E >= 0
    }
    // barrier 1
    __threadfence();
    if (tid == 0) {
        atomicAdd(&bar[0], 1);
        while (atomicAdd(&bar[0], 0) < (int)gridDim.x) {}
    }
    __syncthreads();
    __threadfence();

    // ---- B: S0, S1 ----
    float Emin = __int_as_float(((volatile int*)scal)[0]);
    float T = temp[0];
    float s0 = 0.f, s1 = 0.f;
    for (int i = gtid; i < N_NODES; i += gsz) {
        float dd = (Emin - E[i]) / T;
        float ed = __expf(dd);
        s0 += ed; s1 += ed * dd;
    }
    #pragma unroll
    for (int off = 32; off; off >>= 1) { s0 += __shfl_xor(s0, off); s1 += __shfl_xor(s1, off); }
    __syncthreads();
    if (lane == 0) { fred[wid] = s0; fred[wid + 4] = s1; }
    __syncthreads();
    if (tid == 0) {
        atomicAdd(&scal[1], fred[0] + fred[1] + fred[2] + fred[3]);
        atomicAdd(&scal[2], fred[4] + fred[5] + fred[6] + fred[7]);
    }
    // barrier 2
    __threadfence();
    if (tid == 0) {
        atomicAdd(&bar[1], 1);
        while (atomicAdd(&bar[1], 0) < (int)gridDim.x) {}
    }
    __syncthreads();
    __threadfence();

    // ---- C: gradient, CSR-driven, skip q==0 nodes ----
    float S0 = ((volatile float*)scal)[1];
    float S1 = ((volatile float*)scal)[2];
    float wscale = 2.f * weight[0];
    int lane32 = tid & 31;
    for (int node = blockIdx.x * 8 + (tid >> 5); node < N_NODES; node += gridDim.x * 8) {
        float dd = (Emin - E[node]) / T;
        float qd = (__expf(dd) / S0) * (dd - S1 / S0) / T;
        if (qd == 0.f) continue;
        float cc = wscale * qd;
        float4 od = *(const float4*)(out + node * 128 + lane32 * 4);
        float sx = 0.f, sy = 0.f, sz = 0.f, sw = 0.f;
        int e0 = rowstart[node], e1 = rowstart[node + 1];
        for (int k = e0; k < e1; k++) {
            int s = esrc[k];
            float4 a = *(const float4*)(out + s * 128 + lane32 * 4);
            float vx = cc * (a.x - od.x), vy = cc * (a.y - od.y);
            float vz = cc * (a.z - od.z), vw = cc * (a.w - od.w);
            float* os = out + s * 128 + lane32 * 4;
            atomicAdd(os + 0, vx); atomicAdd(os + 1, vy);
            atomicAdd(os + 2, vz); atomicAdd(os + 3, vw);
            sx += vx; sy += vy; sz += vz; sw += vw;
        }
        float* odp = out + node * 128 + lane32 * 4;
        atomicAdd(odp + 0, -sx); atomicAdd(odp + 1, -sy);
        atomicAdd(odp + 2, -sz); atomicAdd(odp + 3, -sw);
    }
}

extern "C" void kernel_launch(void* const* d_in, const int* in_sizes, int n_in,
                              void* d_out, int out_size, void* d_ws, size_t ws_size,
                              hipStream_t stream) {
    const float* x      = (const float*)d_in[0];
    const int*   ei     = (const int*)d_in[1];
    const float* weight = (const float*)d_in[2];
    const float* temp   = (const float*)d_in[3];
    const float* W      = (const float*)d_in[4];
    const float* b      = (const float*)d_in[5];
    float* out = (float*)d_out;
    float* ws  = (float*)d_ws;

    const int* src = ei;
    const int* dst = ei + N_EDGES;

    unsigned short* htmpb = (unsigned short*)(ws + OFF_HTMPB);
    unsigned short* obf   = (unsigned short*)(ws + OFF_OBF);
    int*   deg      = (int*)(ws + OFF_DEG);
    int*   rowstart = (int*)(ws + OFF_ROWSTART);
    int*   cursor   = (int*)(ws + OFF_CURSOR);
    float* dinv     = ws + OFF_DINV;
    float* Earr     = ws + OFF_E;
    float* scal     = ws + OFF_SCAL;
    int*   bar      = (int*)(ws + OFF_BAR);
    int*   blksum   = (int*)(ws + OFF_BLKSUM);
    int*   esrc     = (int*)(ws + OFF_ESRC);

    k_init<<<NSCANB, 256, 0, stream>>>(ws);
    k_deg_gemm<<<782, 256, 0, stream>>>(x, dst, W, deg, htmpb);
    k_scan1<<<NSCANB, 256, 0, stream>>>(deg, rowstart, blksum, dinv);
    k_scan23<<<NSCANB, 256, 0, stream>>>(rowstart, blksum, cursor);
    k_bucket<<<N_EDGES / 256, 256, 0, stream>>>(src, dst, rowstart, cursor, esrc);
    k_gather<<<6250, 256, 0, stream>>>(htmpb, dinv, b, rowstart, esrc, out, obf);
    k_energy<<<6250, 256, 0, stream>>>(obf, rowstart, esrc, Earr);
    k_tail<<<256, 256, 0, stream>>>(rowstart, esrc, Earr, temp, scal, bar, weight, out);
}

// Round 10
// 264.654 us; speedup vs baseline: 1.2949x; 1.2949x over previous
//
#include <hip/hip_runtime.h>

#define N_NODES 50000
#define N_EDGES 640000
#define NSCANB  196   // ceil(50000/256)

// workspace layout (4B units)
#define OFF_HTMPB    0          // ushort[6400000] bf16 h=xW
#define OFF_OBF      3200000    // ushort[6400000] bf16 copy of out
#define OFF_DEG      6400000    // int[50000]
#define OFF_ROWSTART 6450000    // int[50001]
#define OFF_CURSOR   6500016    // int[50000]
#define OFF_DINV     6550016    // float[50000]
#define OFF_E        6600016    // float[50000]
#define OFF_PMIN     6650016    // float[256] per-block partial min of E
#define OFF_PS0      6650272    // float[256] partial sum e^dd
#define OFF_PS1      6650528    // float[256] partial sum e^dd*dd
#define OFF_ESRC     6650784    // int[640000]

typedef __attribute__((ext_vector_type(4))) short bf16x4;
typedef __attribute__((ext_vector_type(8))) short bf16x8;
typedef __attribute__((ext_vector_type(4))) float f32x4;

__device__ __forceinline__ unsigned short f2bf(float f) {  // RNE
    unsigned u = __float_as_uint(f);
    unsigned r = u + 0x7fffu + ((u >> 16) & 1u);
    return (unsigned short)(r >> 16);
}
__device__ __forceinline__ float bflo(unsigned u) { return __uint_as_float(u << 16); }
__device__ __forceinline__ float bfhi(unsigned u) { return __uint_as_float(u & 0xffff0000u); }

__global__ __launch_bounds__(256) void k_init(int* __restrict__ deg) {
    int i = blockIdx.x * 256 + threadIdx.x;
    if (i < N_NODES) deg[i] = 0;
}

// Fused: degree atomics (grid-stride prologue) + bf16 MFMA GEMM (64-row tile/block).
__global__ __launch_bounds__(256) void k_deg_gemm(const float* __restrict__ x,
                                                  const int* __restrict__ dst,
                                                  const float* __restrict__ W,
                                                  int* __restrict__ deg,
                                                  unsigned short* __restrict__ htmpb) {
    int gtid = blockIdx.x * 256 + threadIdx.x;
    for (int e = gtid; e < N_EDGES; e += 782 * 256) atomicAdd(&deg[dst[e]], 1);

    __shared__ unsigned short wt[128 * 132];   // bf16 W^T
    int tid = threadIdx.x;
    for (int i = tid; i < 4096; i += 256) {
        int k = i >> 5, n4 = (i & 31) * 4;
        float4 v = *(const float4*)(W + k * 128 + n4);
        wt[(n4 + 0) * 132 + k] = f2bf(v.x);
        wt[(n4 + 1) * 132 + k] = f2bf(v.y);
        wt[(n4 + 2) * 132 + k] = f2bf(v.z);
        wt[(n4 + 3) * 132 + k] = f2bf(v.w);
    }
    __syncthreads();

    int wave = tid >> 6, lane = tid & 63, quad = lane >> 4, m16 = lane & 15;
    int r0 = blockIdx.x * 64;
    int arow = r0 + wave * 16 + m16;
    int rowc = arow < N_NODES ? arow : N_NODES - 1;
    f32x4 acc[8];
    #pragma unroll
    for (int c = 0; c < 8; c++) acc[c] = (f32x4){0.f, 0.f, 0.f, 0.f};
    #pragma unroll
    for (int kt = 0; kt < 4; kt++) {
        int koff = kt * 32 + quad * 8;
        float4 xa = *(const float4*)(x + rowc * 128 + koff);
        float4 xb = *(const float4*)(x + rowc * 128 + koff + 4);
        bf16x8 af;
        af[0] = (short)f2bf(xa.x); af[1] = (short)f2bf(xa.y);
        af[2] = (short)f2bf(xa.z); af[3] = (short)f2bf(xa.w);
        af[4] = (short)f2bf(xb.x); af[5] = (short)f2bf(xb.y);
        af[6] = (short)f2bf(xb.z); af[7] = (short)f2bf(xb.w);
        #pragma unroll
        for (int c = 0; c < 8; c++) {
            bf16x4 bl = *(const bf16x4*)(wt + (c * 16 + m16) * 132 + koff);
            bf16x4 bh = *(const bf16x4*)(wt + (c * 16 + m16) * 132 + koff + 4);
            bf16x8 bfrag = __builtin_shufflevector(bl, bh, 0, 1, 2, 3, 4, 5, 6, 7);
            acc[c] = __builtin_amdgcn_mfma_f32_16x16x32_bf16(af, bfrag, acc[c], 0, 0, 0);
        }
    }
    #pragma unroll
    for (int reg = 0; reg < 4; reg++) {
        int grow = r0 + wave * 16 + quad * 4 + reg;
        if (grow < N_NODES) {
            #pragma unroll
            for (int c = 0; c < 8; c++)
                htmpb[grow * 128 + c * 16 + m16] = f2bf(acc[c][reg]);
        }
    }
}

// Fused scan: block vb computes offset = sum deg[0..vb*256) directly (redundant,
// no second kernel), then local exclusive scan + dinv + cursor zero.
__global__ __launch_bounds__(256) void k_scan(const int* __restrict__ deg,
                                              int* __restrict__ rowstart,
                                              int* __restrict__ cursor,
                                              float* __restrict__ dinv) {
    __shared__ int sh[256];
    __shared__ int ired[4];
    int vb = blockIdx.x, tid = threadIdx.x;
    int lane = tid & 63, wid = tid >> 6;
    int base = vb * 256;

    // global offset (redundant per-block reduction over deg[0..base))
    int acc = 0;
    for (int i = tid; i < base; i += 256) acc += deg[i];
    #pragma unroll
    for (int off = 32; off; off >>= 1) acc += __shfl_xor(acc, off);
    if (lane == 0) ired[wid] = acc;
    __syncthreads();
    int offset = ired[0] + ired[1] + ired[2] + ired[3];

    // local exclusive scan
    int i = base + tid;
    int v = (i < N_NODES) ? deg[i] : 0;
    if (i < N_NODES) dinv[i] = rsqrtf((float)(v + 1));  // +1 self-loop
    __syncthreads();
    sh[tid] = v;
    __syncthreads();
    #pragma unroll
    for (int off = 1; off < 256; off <<= 1) {
        int t = (tid >= off) ? sh[tid - off] : 0;
        __syncthreads();
        sh[tid] += t;
        __syncthreads();
    }
    if (i < N_NODES) { rowstart[i] = offset + sh[tid] - v; cursor[i] = 0; }
    if (vb == 0 && tid == 0) rowstart[N_NODES] = N_EDGES;
}

__global__ __launch_bounds__(256) void k_bucket(const int* __restrict__ src,
                                                const int* __restrict__ dst,
                                                const int* __restrict__ rowstart,
                                                int* __restrict__ cursor,
                                                int* __restrict__ esrc) {
    int e = blockIdx.x * 256 + threadIdx.x;
    int d = dst[e];
    int pos = atomicAdd(&cursor[d], 1);
    esrc[rowstart[d] + pos] = src[e];
}

// per node (32 lanes, 4 bf16/lane via uint2), 4 independent load chains.
__global__ __launch_bounds__(256) void k_gather(const unsigned short* __restrict__ htmpb,
                                                const float* __restrict__ dinv,
                                                const float* __restrict__ b,
                                                const int* __restrict__ rowstart,
                                                const int* __restrict__ esrc,
                                                float* __restrict__ out,
                                                unsigned short* __restrict__ obf) {
    int node = blockIdx.x * 8 + (threadIdx.x >> 5);
    int lane = threadIdx.x & 31;
    float di = dinv[node];
    float4 bv = *(const float4*)(b + lane * 4);
    uint2 hv = *(const uint2*)(htmpb + node * 128 + lane * 4);
    float sl = di * di;
    float ax = bv.x + bflo(hv.x) * sl, ay = bv.y + bfhi(hv.x) * sl;
    float az = bv.z + bflo(hv.y) * sl, aw = bv.w + bfhi(hv.y) * sl;
    float cx = 0.f, cy = 0.f, cz = 0.f, cw = 0.f;
    int e0 = rowstart[node], e1 = rowstart[node + 1];
    int k = e0;
    for (; k + 3 < e1; k += 4) {
        int s0 = esrc[k], s1 = esrc[k + 1], s2 = esrc[k + 2], s3 = esrc[k + 3];
        float n0 = di * dinv[s0], n1 = di * dinv[s1];
        float n2 = di * dinv[s2], n3 = di * dinv[s3];
        uint2 u0 = *(const uint2*)(htmpb + s0 * 128 + lane * 4);
        uint2 u1 = *(const uint2*)(htmpb + s1 * 128 + lane * 4);
        uint2 u2 = *(const uint2*)(htmpb + s2 * 128 + lane * 4);
        uint2 u3 = *(const uint2*)(htmpb + s3 * 128 + lane * 4);
        ax += bflo(u0.x) * n0; ay += bfhi(u0.x) * n0;
        az += bflo(u0.y) * n0; aw += bfhi(u0.y) * n0;
        cx += bflo(u1.x) * n1; cy += bfhi(u1.x) * n1;
        cz += bflo(u1.y) * n1; cw += bfhi(u1.y) * n1;
        ax += bflo(u2.x) * n2; ay += bfhi(u2.x) * n2;
        az += bflo(u2.y) * n2; aw += bfhi(u2.y) * n2;
        cx += bflo(u3.x) * n3; cy += bfhi(u3.x) * n3;
        cz += bflo(u3.y) * n3; cw += bfhi(u3.y) * n3;
    }
    for (; k < e1; k++) {
        int s0 = esrc[k];
        float n0 = di * dinv[s0];
        uint2 u0 = *(const uint2*)(htmpb + s0 * 128 + lane * 4);
        ax += bflo(u0.x) * n0; ay += bfhi(u0.x) * n0;
        az += bflo(u0.y) * n0; aw += bfhi(u0.y) * n0;
    }
    ax += cx; ay += cy; az += cz; aw += cw;
    *(float4*)(out + node * 128 + lane * 4) = make_float4(ax, ay, az, aw);
    uint2 pk;
    pk.x = (unsigned)f2bf(ax) | ((unsigned)f2bf(ay) << 16);
    pk.y = (unsigned)f2bf(az) | ((unsigned)f2bf(aw) << 16);
    *(uint2*)(obf + node * 128 + lane * 4) = pk;
}

// per node: E[d] = sum ||out_s - out_d||^2 (bf16 gather, 4 chains, no block barrier)
__global__ __launch_bounds__(256) void k_energy(const unsigned short* __restrict__ obf,
                                                const int* __restrict__ rowstart,
                                                const int* __restrict__ esrc,
                                                float* __restrict__ E) {
    int node = blockIdx.x * 8 + (threadIdx.x >> 5);
    int lane = threadIdx.x & 31;
    uint2 ud = *(const uint2*)(obf + node * 128 + lane * 4);
    float o0 = bflo(ud.x), o1 = bfhi(ud.x), o2 = bflo(ud.y), o3 = bfhi(ud.y);
    float acc = 0.f, acc2 = 0.f;
    int e0 = rowstart[node], e1 = rowstart[node + 1];
    int k = e0;
    for (; k + 3 < e1; k += 4) {
        int s0 = esrc[k], s1 = esrc[k + 1], s2 = esrc[k + 2], s3 = esrc[k + 3];
        uint2 a = *(const uint2*)(obf + s0 * 128 + lane * 4);
        uint2 c = *(const uint2*)(obf + s1 * 128 + lane * 4);
        uint2 g = *(const uint2*)(obf + s2 * 128 + lane * 4);
        uint2 h = *(const uint2*)(obf + s3 * 128 + lane * 4);
        float d0 = bflo(a.x) - o0, d1 = bfhi(a.x) - o1, d2 = bflo(a.y) - o2, d3 = bfhi(a.y) - o3;
        float e4 = bflo(c.x) - o0, e5 = bfhi(c.x) - o1, e6 = bflo(c.y) - o2, e7 = bfhi(c.y) - o3;
        float f0 = bflo(g.x) - o0, f1 = bfhi(g.x) - o1, f2 = bflo(g.y) - o2, f3 = bfhi(g.y) - o3;
        float h4 = bflo(h.x) - o0, h5 = bfhi(h.x) - o1, h6 = bflo(h.y) - o2, h7 = bfhi(h.y) - o3;
        acc  += d0 * d0 + d1 * d1 + d2 * d2 + d3 * d3;
        acc2 += e4 * e4 + e5 * e5 + e6 * e6 + e7 * e7;
        acc  += f0 * f0 + f1 * f1 + f2 * f2 + f3 * f3;
        acc2 += h4 * h4 + h5 * h5 + h6 * h6 + h7 * h7;
    }
    for (; k < e1; k++) {
        int s0 = esrc[k];
        uint2 a = *(const uint2*)(obf + s0 * 128 + lane * 4);
        float d0 = bflo(a.x) - o0, d1 = bfhi(a.x) - o1, d2 = bflo(a.y) - o2, d3 = bfhi(a.y) - o3;
        acc += d0 * d0 + d1 * d1 + d2 * d2 + d3 * d3;
    }
    acc += acc2;
    #pragma unroll
    for (int off = 16; off; off >>= 1) acc += __shfl_xor(acc, off);
    if (lane == 0) E[node] = acc;
}

// 196 blocks: per-block partial min + partial softmax sums (local-min-shifted).
__global__ __launch_bounds__(256) void k_esoft(const float* __restrict__ E,
                                               const float* __restrict__ temp,
                                               float* __restrict__ pmin,
                                               float* __restrict__ ps0,
                                               float* __restrict__ ps1) {
    __shared__ float fred[12];
    int tid = threadIdx.x;
    int i = blockIdx.x * 256 + tid;
    int lane = tid & 63, wid = tid >> 6;
    float e = (i < N_NODES) ? E[i] : 3.402823466e38f;
    float m = e;
    #pragma unroll
    for (int off = 32; off; off >>= 1) m = fminf(m, __shfl_xor(m, off));
    if (lane == 0) fred[wid] = m;
    __syncthreads();
    float bm = fminf(fminf(fred[0], fred[1]), fminf(fred[2], fred[3]));
    float T = temp[0];
    float s0 = 0.f, s1 = 0.f;
    if (i < N_NODES) {
        float dd = (bm - e) / T;
        float ed = __expf(dd);
        s0 = ed; s1 = ed * dd;
    }
    #pragma unroll
    for (int off = 32; off; off >>= 1) { s0 += __shfl_xor(s0, off); s1 += __shfl_xor(s1, off); }
    __syncthreads();
    if (lane == 0) { fred[4 + wid] = s0; fred[8 + wid] = s1; }
    __syncthreads();
    if (tid == 0) {
        pmin[blockIdx.x] = bm;
        ps0[blockIdx.x] = fred[4] + fred[5] + fred[6] + fred[7];
        ps1[blockIdx.x] = fred[8] + fred[9] + fred[10] + fred[11];
    }
}

// Gradient: prologue redundantly combines the 196 partials (online-softmax merge),
// then CSR-driven per-node gradient, skipping q==0 nodes (almost all).
__global__ __launch_bounds__(256) void k_grad(const int* __restrict__ rowstart,
                                              const int* __restrict__ esrc,
                                              const float* __restrict__ E,
                                              const float* __restrict__ temp,
                                              const float* __restrict__ pmin,
                                              const float* __restrict__ ps0,
                                              const float* __restrict__ ps1,
                                              const float* __restrict__ weight,
                                              float* __restrict__ out) {
    __shared__ float fred[12];
    int tid = threadIdx.x;
    int lane = tid & 63, wid = tid >> 6;

    // combine partials: gmin, then S0' = sum e^δ S0_b, S1' = sum e^δ (S1_b + δ S0_b)
    float pm = (tid < NSCANB) ? pmin[tid] : 3.402823466e38f;
    float m = pm;
    #pragma unroll
    for (int off = 32; off; off >>= 1) m = fminf(m, __shfl_xor(m, off));
    if (lane == 0) fred[wid] = m;
    __syncthreads();
    float gmin = fminf(fminf(fred[0], fred[1]), fminf(fred[2], fred[3]));
    float T = temp[0];
    float s0 = 0.f, s1 = 0.f;
    if (tid < NSCANB) {
        float dl = (gmin - pm) / T;        // <= 0
        float ex = __expf(dl);
        float b0 = ps0[tid], b1 = ps1[tid];
        s0 = ex * b0;
        s1 = ex * (b1 + dl * b0);
    }
    #pragma unroll
    for (int off = 32; off; off >>= 1) { s0 += __shfl_xor(s0, off); s1 += __shfl_xor(s1, off); }
    __syncthreads();
    if (lane == 0) { fred[4 + wid] = s0; fred[8 + wid] = s1; }
    __syncthreads();
    float S0 = fred[4] + fred[5] + fred[6] + fred[7];
    float S1 = fred[8] + fred[9] + fred[10] + fred[11];

    // gradient
    float wscale = 2.f * weight[0];
    int lane32 = tid & 31;
    int node = blockIdx.x * 8 + (tid >> 5);
    if (node >= N_NODES) return;
    float dd = (gmin - E[node]) / T;
    float qd = (__expf(dd) / S0) * (dd - S1 / S0) / T;
    if (qd == 0.f) return;
    float cc = wscale * qd;
    float4 od = *(const float4*)(out + node * 128 + lane32 * 4);
    float sx = 0.f, sy = 0.f, sz = 0.f, sw = 0.f;
    int e0 = rowstart[node], e1 = rowstart[node + 1];
    for (int k = e0; k < e1; k++) {
        int s = esrc[k];
        float4 a = *(const float4*)(out + s * 128 + lane32 * 4);
        float vx = cc * (a.x - od.x), vy = cc * (a.y - od.y);
        float vz = cc * (a.z - od.z), vw = cc * (a.w - od.w);
        float* os = out + s * 128 + lane32 * 4;
        atomicAdd(os + 0, vx); atomicAdd(os + 1, vy);
        atomicAdd(os + 2, vz); atomicAdd(os + 3, vw);
        sx += vx; sy += vy; sz += vz; sw += vw;
    }
    float* odp = out + node * 128 + lane32 * 4;
    atomicAdd(odp + 0, -sx); atomicAdd(odp + 1, -sy);
    atomicAdd(odp + 2, -sz); atomicAdd(odp + 3, -sw);
}

extern "C" void kernel_launch(void* const* d_in, const int* in_sizes, int n_in,
                              void* d_out, int out_size, void* d_ws, size_t ws_size,
                              hipStream_t stream) {
    const float* x      = (const float*)d_in[0];
    const int*   ei     = (const int*)d_in[1];
    const float* weight = (const float*)d_in[2];
    const float* temp   = (const float*)d_in[3];
    const float* W      = (const float*)d_in[4];
    const float* b      = (const float*)d_in[5];
    float* out = (float*)d_out;
    float* ws  = (float*)d_ws;

    const int* src = ei;
    const int* dst = ei + N_EDGES;

    unsigned short* htmpb = (unsigned short*)(ws + OFF_HTMPB);
    unsigned short* obf   = (unsigned short*)(ws + OFF_OBF);
    int*   deg      = (int*)(ws + OFF_DEG);
    int*   rowstart = (int*)(ws + OFF_ROWSTART);
    int*   cursor   = (int*)(ws + OFF_CURSOR);
    float* dinv     = ws + OFF_DINV;
    float* Earr     = ws + OFF_E;
    float* pminA    = ws + OFF_PMIN;
    float* ps0A     = ws + OFF_PS0;
    float* ps1A     = ws + OFF_PS1;
    int*   esrc     = (int*)(ws + OFF_ESRC);

    k_init<<<NSCANB, 256, 0, stream>>>(deg);
    k_deg_gemm<<<782, 256, 0, stream>>>(x, dst, W, deg, htmpb);
    k_scan<<<NSCANB, 256, 0, stream>>>(deg, rowstart, cursor, dinv);
    k_bucket<<<N_EDGES / 256, 256, 0, stream>>>(src, dst, rowstart, cursor, esrc);
    k_gather<<<6250, 256, 0, stream>>>(htmpb, dinv, b, rowstart, esrc, out, obf);
    k_energy<<<6250, 256, 0, stream>>>(obf, rowstart, esrc, Earr);
    k_esoft<<<NSCANB, 256, 0, stream>>>(Earr, temp, pminA, ps0A, ps1A);
    k_grad<<<6250, 256, 0, stream>>>(rowstart, esrc, Earr, temp, pminA, ps0A, ps1A, weight, out);
}